// Round 9
// baseline (126.062 us; speedup 1.0000x reference)
//
#include <hip/hip_runtime.h>
#include <math.h>

#define CCH 4096
#define SP 891

typedef __attribute__((ext_vector_type(8))) short short8;
typedef __attribute__((ext_vector_type(4))) float f32x4;

__device__ __forceinline__ unsigned int pack_bf2(float a, float b) {
  unsigned int ua = __builtin_bit_cast(unsigned int, a);
  unsigned int ub = __builtin_bit_cast(unsigned int, b);
  ua = (ua + 0x7fffu + ((ua >> 16) & 1u)) >> 16;
  ub = (ub + 0x7fffu + ((ub >> 16) & 1u)) >> 16;
  return ua | (ub << 16);
}

// ---------- setup: members + rowSid + cnt/off + inv1 (80 blocks x 64) ----------
__global__ void k_setup(const int* __restrict__ im0, const int* __restrict__ im1,
                        int* cnt0, int* off0, int* cnt1, int* off1,
                        int* mem0, int* mem1, int* rs0, int* rs1, int* inv1) {
  int cb = blockIdx.x;
  int level = (cb >= 64) ? 1 : 0;
  int c = level ? cb - 64 : cb;
  const int* im = level ? im1 : im0;
  int* members = level ? mem1 : mem0;
  int* rs = level ? rs1 : rs0;
  int lane = threadIdx.x;  // 64
  int lt = 0;
  for (int ch = lane; ch < CCH; ch += 64) lt += (im[ch] < c) ? 1 : 0;
  for (int o = 32; o; o >>= 1) lt += __shfl_xor(lt, o, 64);
  int base = lt;
  int cnt = 0;
  for (int chunk = 0; chunk < CCH; chunk += 64) {
    int ch = chunk + lane;
    bool m = (im[ch] == c);
    unsigned long long mk = __ballot(m);
    int pos = __popcll(mk & ((1ull << lane) - 1ull));
    if (m) members[base + cnt + pos] = ch;
    cnt += __popcll(mk);
  }
  int n = cnt;
  if (lane == 0) {
    if (level) { cnt1[c] = n; off1[c] = base; }
    else       { cnt0[c] = n; off0[c] = base; }
  }
  __syncthreads();
  for (int r = lane; r < n; r += 64) {
    #pragma unroll
    for (int q = 0; q < 8; q++) {
      int p = 8 * r + q;
      int b = p / n, j = p - b * n;
      int sid = b * CCH + members[base + j];
      rs[(size_t)(base + r) * 8 + q] = sid;
      if (level) inv1[sid] = ((base + r) << 3) | q;   // row1<<3 | q1 (bijection)
    }
  }
}

// ---------- pack rep slices into fragment-major bf16 tables (B operands) ----------
__global__ void k_brep(const float* __restrict__ X,
    const int* __restrict__ off0, const int* __restrict__ off1,
    const int* __restrict__ rs0, const int* __restrict__ rs1,
    uint4* __restrict__ Bfrag0, uint4* __restrict__ Bfrag1) {
  int gid = blockIdx.x * 4 + (threadIdx.x >> 6);  // 0..39
  int l = threadIdx.x & 63;
  int lrow = l & 15, hi = l >> 4;
  int level = (gid >= 32) ? 1 : 0;
  int q = level ? (gid - 32) : (gid >> 2);
  int ct = level ? 0 : (gid & 3);
  int cc = ct * 16 + lrow;
  int base = level ? off1[cc] : off0[cc];
  int sid = (level ? rs1 : rs0)[(size_t)base * 8 + q];
  const float* ap = X + (size_t)sid * SP + hi * 8;
  uint4* dst = (level ? Bfrag1 + (size_t)(q * 28) * 64
                      : Bfrag0 + (size_t)((q * 4 + ct) * 28) * 64) + l;
  #pragma unroll 3
  for (int kc = 0; kc < 27; kc++) {
    float4 fa0 = *(const float4*)(ap + kc * 32);
    float4 fa1 = *(const float4*)(ap + kc * 32 + 4);
    uint4 ua;
    ua.x = pack_bf2(fa0.x, fa0.y); ua.y = pack_bf2(fa0.z, fa0.w);
    ua.z = pack_bf2(fa1.x, fa1.y); ua.w = pack_bf2(fa1.z, fa1.w);
    dst[kc * 64] = ua;
  }
  {
    float4 fa0, fa1;
    if (hi == 3) {
      fa0 = make_float4(ap[864], ap[865], ap[866], 0.f);
      fa1 = make_float4(0.f, 0.f, 0.f, 0.f);
    } else {
      fa0 = *(const float4*)(ap + 864);
      fa1 = *(const float4*)(ap + 868);
    }
    uint4 ua;
    ua.x = pack_bf2(fa0.x, fa0.y); ua.y = pack_bf2(fa0.z, fa0.w);
    ua.z = pack_bf2(fa1.x, fa1.y); ua.w = pack_bf2(fa1.z, fa1.w);
    dst[27 * 64] = ua;
  }
}

// ---------- repack: X -> Y0 (L0-fragment-interleaved) + Y1 (L1 slice-runs) + sn2 ----------
// grid (256, 8): block = (rt0, q). 16 slices per block, LDS transpose.
__global__ __launch_bounds__(256) void k_pack(const float* __restrict__ X,
    const int* __restrict__ rs0, const int* __restrict__ inv1,
    uint4* __restrict__ Y0, uint4* __restrict__ Y1, float* __restrict__ sn2) {
  __shared__ unsigned short T[16][912];   // row stride 912 -> 2-way-max bank alias
  __shared__ int s_sid[16];
  __shared__ int s_inv[16];
  const int rt0 = blockIdx.x, q = blockIdx.y, tid = threadIdx.x;
  if (tid < 16) {
    int sid = rs0[(size_t)(rt0 * 16 + tid) * 8 + q];
    s_sid[tid] = sid;
    s_inv[tid] = inv1[sid];
  }
  __syncthreads();
  const int i = tid >> 4, j = tid & 15;
  const float* sp = X + (size_t)s_sid[i] * SP;
  float s2 = 0.f;
  #pragma unroll
  for (int kcc = 0; kcc < 14; kcc++) {
    int e = kcc * 64 + j * 4;
    float4 v;
    if (kcc < 13 || j < 14)      v = *(const float4*)(sp + e);
    else if (j == 14)            v = make_float4(sp[888], sp[889], sp[890], 0.f);
    else                         v = make_float4(0.f, 0.f, 0.f, 0.f);
    s2 += v.x * v.x + v.y * v.y + v.z * v.z + v.w * v.w;
    uint2 u;
    u.x = pack_bf2(v.x, v.y); u.y = pack_bf2(v.z, v.w);
    *(uint2*)&T[i][e] = u;
  }
  s2 += __shfl_xor(s2, 1, 16); s2 += __shfl_xor(s2, 2, 16);
  s2 += __shfl_xor(s2, 4, 16); s2 += __shfl_xor(s2, 8, 16);
  if (j == 0) sn2[s_sid[i]] = s2;
  __syncthreads();
  // Y0: [(q*256+rt0)*28 + kc] * 64 + l  (lane l = (lrow, hi))
  uint4* y0 = Y0 + (size_t)((q * 256 + rt0) * 28) * 64;
  #pragma unroll
  for (int it = 0; it < 7; it++) {
    int pos = it * 256 + tid;           // 0..1791
    int kc = pos >> 6, l = pos & 63;
    int lrow = l & 15, hi = l >> 4;
    y0[pos] = *(const uint4*)&T[lrow][kc * 32 + hi * 8];
  }
  // Y1: per-slice run of 112 uint4 at (q1*4096 + row1)
  #pragma unroll
  for (int it = 0; it < 7; it++) {
    int p = it * 256 + tid;             // 0..1791
    int si = p / 112, pp = p - si * 112;
    int kc = pp >> 2, hi = pp & 3;
    uint4 v = *(const uint4*)&T[si][kc * 32 + hi * 8];
    int inv = s_inv[si];
    int row1 = inv >> 3, q1 = inv & 7;
    Y1[((size_t)q1 * CCH + row1) * 112 + pp] = v;
  }
}

// ---------- register-direct MFMA GEMM from pre-interleaved operands ----------
__global__ __launch_bounds__(256) void k_gemm_all(
    const uint4* __restrict__ Y0, const uint4* __restrict__ Y1,
    const uint4* __restrict__ Bfrag0, const uint4* __restrict__ Bfrag1,
    float* __restrict__ P8_0, float* __restrict__ P8_1) {
  const int q = blockIdx.y, tid = threadIdx.x;
  const int l = tid & 63, w = tid >> 6;
  const int lrow = l & 15, hi = l >> 4;
  if (blockIdx.x < 128) {
    // L0: TM=32 (2 row tiles), N=64 (2 waves x 2 col frags)
    const int wm = w & 1, wn = w >> 1;
    const int rowTile = blockIdx.x * 2 + wm;
    const uint4* aB = Y0 + (size_t)((q * 256 + rowTile) * 28) * 64 + l;
    const uint4* b0 = Bfrag0 + (size_t)((q * 4 + wn * 2) * 28) * 64 + l;
    const uint4* b1 = b0 + 28 * 64;
    f32x4 acc0 = {0.f, 0.f, 0.f, 0.f}, acc1 = {0.f, 0.f, 0.f, 0.f};
    uint4 Ab[6], B0b[6], B1b[6];
    #pragma unroll
    for (int d = 0; d < 6; d++) { Ab[d] = aB[d * 64]; B0b[d] = b0[d * 64]; B1b[d] = b1[d * 64]; }
    #pragma unroll
    for (int kc = 0; kc < 28; kc++) {
      int d = kc % 6;
      short8 a8 = __builtin_bit_cast(short8, Ab[d]);
      acc0 = __builtin_amdgcn_mfma_f32_16x16x32_bf16(a8, __builtin_bit_cast(short8, B0b[d]), acc0, 0, 0, 0);
      acc1 = __builtin_amdgcn_mfma_f32_16x16x32_bf16(a8, __builtin_bit_cast(short8, B1b[d]), acc1, 0, 0, 0);
      int nk = kc + 6;
      if (nk < 28) { Ab[d] = aB[nk * 64]; B0b[d] = b0[nk * 64]; B1b[d] = b1[nk * 64]; }
    }
    #pragma unroll
    for (int r = 0; r < 4; r++) {
      int row = rowTile * 16 + hi * 4 + r;
      float* dst = P8_0 + ((size_t)q * CCH + row) * 64;
      dst[wn * 32 + lrow] = acc0[r];
      dst[wn * 32 + 16 + lrow] = acc1[r];
    }
  } else {
    // L1: TM=64 (4 waves = 4 row tiles), N=16
    const int bx = blockIdx.x - 128;
    const int rt1 = bx * 4 + w;
    const uint4* aB = Y1 + ((size_t)q * CCH + rt1 * 16 + lrow) * 112 + hi;
    const uint4* bq = Bfrag1 + (size_t)(q * 28) * 64 + l;
    f32x4 acc = {0.f, 0.f, 0.f, 0.f};
    uint4 Ab[6], Bb[6];
    #pragma unroll
    for (int d = 0; d < 6; d++) { Ab[d] = aB[d * 4]; Bb[d] = bq[d * 64]; }
    #pragma unroll
    for (int kc = 0; kc < 28; kc++) {
      int d = kc % 6;
      acc = __builtin_amdgcn_mfma_f32_16x16x32_bf16(
          __builtin_bit_cast(short8, Ab[d]), __builtin_bit_cast(short8, Bb[d]), acc, 0, 0, 0);
      int nk = kc + 6;
      if (nk < 28) { Ab[d] = aB[nk * 4]; Bb[d] = bq[nk * 64]; }
    }
    #pragma unroll
    for (int r = 0; r < 4; r++) {
      int row = rt1 * 16 + hi * 4 + r;
      P8_1[((size_t)q * CCH + row) * 16 + lrow] = acc[r];
    }
  }
}

// ---------- per-cluster epilogue, both levels in one dispatch ----------
template<int K>
__device__ __forceinline__ void fin_body(const float* __restrict__ P8,
    const float* __restrict__ sn2, const int* __restrict__ rs,
    const int* __restrict__ cnt, const int* __restrict__ off,
    double* __restrict__ clLoss, int c) {
  __shared__ float pcc[4096];
  __shared__ float red[256];
  __shared__ double redd[256];
  __shared__ float s_conc;
  const int n = cnt[c], base = off[c];
  const int tid = threadIdx.x;
  float rn0 = 0.f;
  #pragma unroll
  for (int qq = 0; qq < 8; qq++) rn0 += sn2[rs[(size_t)base * 8 + qq]];
  float t = 0.f;
  for (int r = tid; r < n; r += 256) {
    float pd = 0.f, rn = 0.f;
    #pragma unroll
    for (int qq = 0; qq < 8; qq++) {
      pd += P8[((size_t)qq * CCH + base + r) * K + c];
      rn += sn2[rs[(size_t)(base + r) * 8 + qq]];
    }
    pcc[r] = pd;
    if (r > 0) {
      float d2 = rn - 2.f * pd + rn0;
      t += (d2 > 0.f) ? sqrtf(d2) : 0.f;
    }
  }
  red[tid] = t; __syncthreads();
  for (int o = 128; o; o >>= 1) { if (tid < o) red[tid] += red[tid + o]; __syncthreads(); }
  if (tid == 0) s_conc = red[0] / ((float)n * logf((float)n + 10.f));
  __syncthreads();
  const float invc = 1.f / s_conc;
  const int wv = tid >> 6, lane = tid & 63;
  const int sub = (K == 64) ? 0 : (lane >> 4);
  const int cc = lane & (K - 1);
  constexpr int RPI = (K == 64) ? 4 : 16;
  double acc = 0.0;
  for (int r = wv * (RPI / 4) + sub; r < n; r += RPI) {
    float s = 0.f;
    #pragma unroll
    for (int qq = 0; qq < 8; qq++) s += P8[((size_t)qq * CCH + base + r) * K + cc];
    float lg = s * invc;
    float m = lg;
    #pragma unroll
    for (int o = K / 2; o; o >>= 1) m = fmaxf(m, __shfl_xor(m, o, K));
    float e = expf(lg - m);
    float se = e;
    #pragma unroll
    for (int o = K / 2; o; o >>= 1) se += __shfl_xor(se, o, K);
    if (cc == 0) acc += (double)(m + logf(se)) - (double)(pcc[r] * invc);
  }
  redd[tid] = acc; __syncthreads();
  for (int o = 128; o; o >>= 1) { if (tid < o) redd[tid] += redd[tid + o]; __syncthreads(); }
  if (tid == 0) clLoss[c] = redd[0] / (double)n;
}

__global__ __launch_bounds__(256) void k_fin_all(const float* __restrict__ P8_0,
    const float* __restrict__ P8_1, const float* __restrict__ sn2,
    const int* __restrict__ rs0, const int* __restrict__ rs1,
    const int* __restrict__ cnt0, const int* __restrict__ off0,
    const int* __restrict__ cnt1, const int* __restrict__ off1,
    double* __restrict__ cl0, double* __restrict__ cl1) {
  if (blockIdx.x < 64) fin_body<64>(P8_0, sn2, rs0, cnt0, off0, cl0, blockIdx.x);
  else                 fin_body<16>(P8_1, sn2, rs1, cnt1, off1, cl1, blockIdx.x - 64);
}

// ---------- final scalars ----------
__global__ void k_final(const double* __restrict__ cl0, const double* __restrict__ cl1,
                        float* __restrict__ out) {
  if (threadIdx.x == 0) {
    double s0 = 0.0, s1 = 0.0;
    for (int i = 0; i < 64; i++) s0 += cl0[i];
    for (int i = 0; i < 16; i++) s1 += cl1[i];
    out[0] = (float)(s0 / 4096.0);
    out[1] = (float)(s1 / 8192.0);
  }
}

extern "C" void kernel_launch(void* const* d_in, const int* in_sizes, int n_in,
                              void* d_out, int out_size, void* d_ws, size_t ws_size,
                              hipStream_t stream) {
  const float* X = (const float*)d_in[0];
  const int* im0 = (const int*)d_in[1];
  const int* im1 = (const int*)d_in[2];
  float* out = (float*)d_out;

  char* w = (char*)d_ws;
  auto alloc = [&](size_t bytes) -> char* {
    char* p = w; w += (bytes + 255) & ~(size_t)255; return p;
  };
  int*    cnt0  = (int*)alloc(64 * 4);
  int*    off0  = (int*)alloc(64 * 4);
  int*    cnt1  = (int*)alloc(16 * 4);
  int*    off1  = (int*)alloc(16 * 4);
  int*    mem0  = (int*)alloc((size_t)CCH * 4);
  int*    mem1  = (int*)alloc((size_t)CCH * 4);
  int*    rs0   = (int*)alloc((size_t)CCH * 8 * 4);
  int*    rs1   = (int*)alloc((size_t)CCH * 8 * 4);
  int*    inv1  = (int*)alloc((size_t)8 * CCH * 4);
  float*  sn2   = (float*)alloc((size_t)8 * CCH * 4);
  uint4*  Bfrag0 = (uint4*)alloc((size_t)32 * 28 * 64 * 16);
  uint4*  Bfrag1 = (uint4*)alloc((size_t)8 * 28 * 64 * 16);
  uint4*  Y0    = (uint4*)alloc((size_t)8 * 256 * 28 * 64 * 16);   // 58.7 MB
  uint4*  Y1    = (uint4*)alloc((size_t)8 * CCH * 112 * 16);       // 58.7 MB
  float*  P8_0  = (float*)alloc((size_t)8 * CCH * 64 * 4);
  float*  P8_1  = (float*)alloc((size_t)8 * CCH * 16 * 4);
  double* cl0   = (double*)alloc(64 * 8);
  double* cl1   = (double*)alloc(16 * 8);

  k_setup<<<80, 64, 0, stream>>>(im0, im1, cnt0, off0, cnt1, off1, mem0, mem1, rs0, rs1, inv1);
  k_brep<<<10, 256, 0, stream>>>(X, off0, off1, rs0, rs1, Bfrag0, Bfrag1);
  k_pack<<<dim3(256, 8), 256, 0, stream>>>(X, rs0, inv1, Y0, Y1, sn2);
  k_gemm_all<<<dim3(192, 8), 256, 0, stream>>>(Y0, Y1, Bfrag0, Bfrag1, P8_0, P8_1);
  k_fin_all<<<80, 256, 0, stream>>>(P8_0, P8_1, sn2, rs0, rs1, cnt0, off0, cnt1, off1, cl0, cl1);
  k_final<<<1, 64, 0, stream>>>(cl0, cl1, out);
}

// Round 10
// 120.250 us; speedup vs baseline: 1.0483x; 1.0483x over previous
//
#include <hip/hip_runtime.h>
#include <math.h>

#define CCH 4096
#define SP 891
#define NSL 32768

typedef __attribute__((ext_vector_type(8))) short short8;
typedef __attribute__((ext_vector_type(4))) float f32x4;

__device__ __forceinline__ unsigned int pack_bf2(float a, float b) {
  unsigned int ua = __builtin_bit_cast(unsigned int, a);
  unsigned int ub = __builtin_bit_cast(unsigned int, b);
  ua = (ua + 0x7fffu + ((ua >> 16) & 1u)) >> 16;
  ub = (ub + 0x7fffu + ((ub >> 16) & 1u)) >> 16;
  return ua | (ub << 16);
}

// ---------- setup: members + rowSid + cnt/off + inv1 (80 blocks x 64) ----------
__global__ void k_setup(const int* __restrict__ im0, const int* __restrict__ im1,
                        int* cnt0, int* off0, int* cnt1, int* off1,
                        int* mem0, int* mem1, int* rs0, int* rs1, int* inv1) {
  int cb = blockIdx.x;
  int level = (cb >= 64) ? 1 : 0;
  int c = level ? cb - 64 : cb;
  const int* im = level ? im1 : im0;
  int* members = level ? mem1 : mem0;
  int* rs = level ? rs1 : rs0;
  int lane = threadIdx.x;  // 64
  int lt = 0;
  for (int ch = lane; ch < CCH; ch += 64) lt += (im[ch] < c) ? 1 : 0;
  for (int o = 32; o; o >>= 1) lt += __shfl_xor(lt, o, 64);
  int base = lt;
  int cnt = 0;
  for (int chunk = 0; chunk < CCH; chunk += 64) {
    int ch = chunk + lane;
    bool m = (im[ch] == c);
    unsigned long long mk = __ballot(m);
    int pos = __popcll(mk & ((1ull << lane) - 1ull));
    if (m) members[base + cnt + pos] = ch;
    cnt += __popcll(mk);
  }
  int n = cnt;
  if (lane == 0) {
    if (level) { cnt1[c] = n; off1[c] = base; }
    else       { cnt0[c] = n; off0[c] = base; }
  }
  __syncthreads();
  for (int r = lane; r < n; r += 64) {
    #pragma unroll
    for (int q = 0; q < 8; q++) {
      int p = 8 * r + q;
      int b = p / n, j = p - b * n;
      int sid = b * CCH + members[base + j];
      rs[(size_t)(base + r) * 8 + q] = sid;
      if (level) inv1[sid] = ((base + r) << 3) | q;   // row1<<3 | q1 (bijection)
    }
  }
}

// ---------- pack rep slices into fragment-major bf16 tables (B operands) ----------
__global__ void k_brep(const float* __restrict__ X,
    const int* __restrict__ off0, const int* __restrict__ off1,
    const int* __restrict__ rs0, const int* __restrict__ rs1,
    uint4* __restrict__ Bfrag0, uint4* __restrict__ Bfrag1) {
  int gid = blockIdx.x * 4 + (threadIdx.x >> 6);  // 0..39
  int l = threadIdx.x & 63;
  int lrow = l & 15, hi = l >> 4;
  int level = (gid >= 32) ? 1 : 0;
  int q = level ? (gid - 32) : (gid >> 2);
  int ct = level ? 0 : (gid & 3);
  int cc = ct * 16 + lrow;
  int base = level ? off1[cc] : off0[cc];
  int sid = (level ? rs1 : rs0)[(size_t)base * 8 + q];
  const float* ap = X + (size_t)sid * SP + hi * 8;
  uint4* dst = (level ? Bfrag1 + (size_t)(q * 28) * 64
                      : Bfrag0 + (size_t)((q * 4 + ct) * 28) * 64) + l;
  #pragma unroll 3
  for (int kc = 0; kc < 27; kc++) {
    float4 fa0 = *(const float4*)(ap + kc * 32);
    float4 fa1 = *(const float4*)(ap + kc * 32 + 4);
    uint4 ua;
    ua.x = pack_bf2(fa0.x, fa0.y); ua.y = pack_bf2(fa0.z, fa0.w);
    ua.z = pack_bf2(fa1.x, fa1.y); ua.w = pack_bf2(fa1.z, fa1.w);
    dst[kc * 64] = ua;
  }
  {
    float4 fa0, fa1;
    if (hi == 3) {
      fa0 = make_float4(ap[864], ap[865], ap[866], 0.f);
      fa1 = make_float4(0.f, 0.f, 0.f, 0.f);
    } else {
      fa0 = *(const float4*)(ap + 864);
      fa1 = *(const float4*)(ap + 868);
    }
    uint4 ua;
    ua.x = pack_bf2(fa0.x, fa0.y); ua.y = pack_bf2(fa0.z, fa0.w);
    ua.z = pack_bf2(fa1.x, fa1.y); ua.w = pack_bf2(fa1.z, fa1.w);
    dst[27 * 64] = ua;
  }
}

// ---------- repack: X -> Y0 + Y1 + sn2 halves; split by k-half (grid 256x8x2) ----------
__global__ __launch_bounds__(256) void k_pack(const float* __restrict__ X,
    const int* __restrict__ rs0, const int* __restrict__ inv1,
    uint4* __restrict__ Y0, uint4* __restrict__ Y1, float* __restrict__ sn2h) {
  __shared__ __align__(16) unsigned short T[16][472];  // 944B rows: 16B-aligned, 2-way-max banks
  __shared__ int s_sid[16];
  __shared__ int s_inv[16];
  const int rt0 = blockIdx.x, q = blockIdx.y, h = blockIdx.z, tid = threadIdx.x;
  if (tid < 16) {
    int sid = rs0[(size_t)(rt0 * 16 + tid) * 8 + q];
    s_sid[tid] = sid;
    s_inv[tid] = inv1[sid];
  }
  __syncthreads();
  const int i = tid >> 4, j = tid & 15;
  const float* sp = X + (size_t)s_sid[i] * SP + h * 448;
  float s2 = 0.f;
  #pragma unroll
  for (int kcc = 0; kcc < 7; kcc++) {
    int el = kcc * 64 + j * 4;
    float4 v;
    if (h == 0 || kcc < 6 || j < 14)  v = *(const float4*)(sp + el);
    else if (j == 14)                 v = make_float4(sp[el], sp[el + 1], sp[el + 2], 0.f);
    else                              v = make_float4(0.f, 0.f, 0.f, 0.f);
    s2 += v.x * v.x + v.y * v.y + v.z * v.z + v.w * v.w;
    uint2 u;
    u.x = pack_bf2(v.x, v.y); u.y = pack_bf2(v.z, v.w);
    *(uint2*)&T[i][el] = u;
  }
  s2 += __shfl_xor(s2, 1, 16); s2 += __shfl_xor(s2, 2, 16);
  s2 += __shfl_xor(s2, 4, 16); s2 += __shfl_xor(s2, 8, 16);
  if (j == 0) sn2h[(size_t)h * NSL + s_sid[i]] = s2;
  __syncthreads();
  // Y0 half: positions kc_local*64 + l, kc = 14h + kc_local
  uint4* y0 = Y0 + (size_t)((q * 256 + rt0) * 28) * 64 + (size_t)h * 896;
  #pragma unroll
  for (int it = 0; it < 4; it++) {
    int pos = it * 256 + tid;
    if (pos < 896) {
      int kc_l = pos >> 6, l = pos & 63;
      int lrow = l & 15, hi = l >> 4;
      y0[pos] = *(const uint4*)&T[lrow][kc_l * 32 + hi * 8];
    }
  }
  // Y1 half: per-slice 56-uint4 sub-runs
  #pragma unroll
  for (int it = 0; it < 4; it++) {
    int p = it * 256 + tid;
    if (p < 896) {
      int si = p / 56, pp_l = p - si * 56;
      int kc_l = pp_l >> 2, hi = pp_l & 3;
      uint4 v = *(const uint4*)&T[si][kc_l * 32 + hi * 8];
      int inv = s_inv[si];
      int row1 = inv >> 3, q1 = inv & 7;
      Y1[((size_t)q1 * CCH + row1) * 112 + h * 56 + pp_l] = v;
    }
  }
}

// ---------- register-direct MFMA GEMM from pre-interleaved operands ----------
__global__ __launch_bounds__(256) void k_gemm_all(
    const uint4* __restrict__ Y0, const uint4* __restrict__ Y1,
    const uint4* __restrict__ Bfrag0, const uint4* __restrict__ Bfrag1,
    float* __restrict__ P8_0, float* __restrict__ P8_1) {
  const int q = blockIdx.y, tid = threadIdx.x;
  const int l = tid & 63, w = tid >> 6;
  const int lrow = l & 15, hi = l >> 4;
  if (blockIdx.x < 128) {
    const int wm = w & 1, wn = w >> 1;
    const int rowTile = blockIdx.x * 2 + wm;
    const uint4* aB = Y0 + (size_t)((q * 256 + rowTile) * 28) * 64 + l;
    const uint4* b0 = Bfrag0 + (size_t)((q * 4 + wn * 2) * 28) * 64 + l;
    const uint4* b1 = b0 + 28 * 64;
    f32x4 acc0 = {0.f, 0.f, 0.f, 0.f}, acc1 = {0.f, 0.f, 0.f, 0.f};
    uint4 Ab[6], B0b[6], B1b[6];
    #pragma unroll
    for (int d = 0; d < 6; d++) { Ab[d] = aB[d * 64]; B0b[d] = b0[d * 64]; B1b[d] = b1[d * 64]; }
    #pragma unroll
    for (int kc = 0; kc < 28; kc++) {
      int d = kc % 6;
      short8 a8 = __builtin_bit_cast(short8, Ab[d]);
      acc0 = __builtin_amdgcn_mfma_f32_16x16x32_bf16(a8, __builtin_bit_cast(short8, B0b[d]), acc0, 0, 0, 0);
      acc1 = __builtin_amdgcn_mfma_f32_16x16x32_bf16(a8, __builtin_bit_cast(short8, B1b[d]), acc1, 0, 0, 0);
      int nk = kc + 6;
      if (nk < 28) { Ab[d] = aB[nk * 64]; B0b[d] = b0[nk * 64]; B1b[d] = b1[nk * 64]; }
    }
    #pragma unroll
    for (int r = 0; r < 4; r++) {
      int row = rowTile * 16 + hi * 4 + r;
      float* dst = P8_0 + ((size_t)q * CCH + row) * 64;
      dst[wn * 32 + lrow] = acc0[r];
      dst[wn * 32 + 16 + lrow] = acc1[r];
    }
  } else {
    const int bx = blockIdx.x - 128;
    const int rt1 = bx * 4 + w;
    const uint4* aB = Y1 + ((size_t)q * CCH + rt1 * 16 + lrow) * 112 + hi;
    const uint4* bq = Bfrag1 + (size_t)(q * 28) * 64 + l;
    f32x4 acc = {0.f, 0.f, 0.f, 0.f};
    uint4 Ab[6], Bb[6];
    #pragma unroll
    for (int d = 0; d < 6; d++) { Ab[d] = aB[d * 4]; Bb[d] = bq[d * 64]; }
    #pragma unroll
    for (int kc = 0; kc < 28; kc++) {
      int d = kc % 6;
      acc = __builtin_amdgcn_mfma_f32_16x16x32_bf16(
          __builtin_bit_cast(short8, Ab[d]), __builtin_bit_cast(short8, Bb[d]), acc, 0, 0, 0);
      int nk = kc + 6;
      if (nk < 28) { Ab[d] = aB[nk * 4]; Bb[d] = bq[nk * 64]; }
    }
    #pragma unroll
    for (int r = 0; r < 4; r++) {
      int row = rt1 * 16 + hi * 4 + r;
      P8_1[((size_t)q * CCH + row) * 16 + lrow] = acc[r];
    }
  }
}

// ---------- per-cluster epilogue (512 threads), both levels in one dispatch ----------
template<int K>
__device__ __forceinline__ void fin_body(const float* __restrict__ P8,
    const float* __restrict__ sn2h, const int* __restrict__ rs,
    const int* __restrict__ cnt, const int* __restrict__ off,
    double* __restrict__ clLoss, int c) {
  __shared__ float pcc[4096];
  __shared__ float red[512];
  __shared__ double redd[512];
  __shared__ float s_conc;
  const int n = cnt[c], base = off[c];
  const int tid = threadIdx.x;
  float rn0 = 0.f;
  #pragma unroll
  for (int qq = 0; qq < 8; qq++) {
    int sid = rs[(size_t)base * 8 + qq];
    rn0 += sn2h[sid] + sn2h[NSL + sid];
  }
  float t = 0.f;
  for (int r = tid; r < n; r += 512) {
    float pd = 0.f, rn = 0.f;
    #pragma unroll
    for (int qq = 0; qq < 8; qq++) {
      pd += P8[((size_t)qq * CCH + base + r) * K + c];
      int sid = rs[(size_t)(base + r) * 8 + qq];
      rn += sn2h[sid] + sn2h[NSL + sid];
    }
    pcc[r] = pd;
    if (r > 0) {
      float d2 = rn - 2.f * pd + rn0;
      t += (d2 > 0.f) ? sqrtf(d2) : 0.f;
    }
  }
  red[tid] = t; __syncthreads();
  for (int o = 256; o; o >>= 1) { if (tid < o) red[tid] += red[tid + o]; __syncthreads(); }
  if (tid == 0) s_conc = red[0] / ((float)n * logf((float)n + 10.f));
  __syncthreads();
  const float invc = 1.f / s_conc;
  const int wv = tid >> 6, lane = tid & 63;           // 8 waves
  const int sub = (K == 64) ? 0 : (lane >> 4);
  const int cc = lane & (K - 1);
  constexpr int RPI = 8 * (64 / K);                   // rows per iteration (8 waves)
  double acc = 0.0;
  for (int r = wv * (64 / K) + sub; r < n; r += RPI) {
    float s = 0.f;
    #pragma unroll
    for (int qq = 0; qq < 8; qq++) s += P8[((size_t)qq * CCH + base + r) * K + cc];
    float lg = s * invc;
    float m = lg;
    #pragma unroll
    for (int o = K / 2; o; o >>= 1) m = fmaxf(m, __shfl_xor(m, o, K));
    float e = expf(lg - m);
    float se = e;
    #pragma unroll
    for (int o = K / 2; o; o >>= 1) se += __shfl_xor(se, o, K);
    if (cc == 0) acc += (double)(m + logf(se)) - (double)(pcc[r] * invc);
  }
  redd[tid] = acc; __syncthreads();
  for (int o = 256; o; o >>= 1) { if (tid < o) redd[tid] += redd[tid + o]; __syncthreads(); }
  if (tid == 0) clLoss[c] = redd[0] / (double)n;
}

__global__ __launch_bounds__(512) void k_fin_all(const float* __restrict__ P8_0,
    const float* __restrict__ P8_1, const float* __restrict__ sn2h,
    const int* __restrict__ rs0, const int* __restrict__ rs1,
    const int* __restrict__ cnt0, const int* __restrict__ off0,
    const int* __restrict__ cnt1, const int* __restrict__ off1,
    double* __restrict__ cl0, double* __restrict__ cl1) {
  if (blockIdx.x < 64) fin_body<64>(P8_0, sn2h, rs0, cnt0, off0, cl0, blockIdx.x);
  else                 fin_body<16>(P8_1, sn2h, rs1, cnt1, off1, cl1, blockIdx.x - 64);
}

// ---------- final scalars ----------
__global__ void k_final(const double* __restrict__ cl0, const double* __restrict__ cl1,
                        float* __restrict__ out) {
  if (threadIdx.x == 0) {
    double s0 = 0.0, s1 = 0.0;
    for (int i = 0; i < 64; i++) s0 += cl0[i];
    for (int i = 0; i < 16; i++) s1 += cl1[i];
    out[0] = (float)(s0 / 4096.0);
    out[1] = (float)(s1 / 8192.0);
  }
}

extern "C" void kernel_launch(void* const* d_in, const int* in_sizes, int n_in,
                              void* d_out, int out_size, void* d_ws, size_t ws_size,
                              hipStream_t stream) {
  const float* X = (const float*)d_in[0];
  const int* im0 = (const int*)d_in[1];
  const int* im1 = (const int*)d_in[2];
  float* out = (float*)d_out;

  char* w = (char*)d_ws;
  auto alloc = [&](size_t bytes) -> char* {
    char* p = w; w += (bytes + 255) & ~(size_t)255; return p;
  };
  int*    cnt0  = (int*)alloc(64 * 4);
  int*    off0  = (int*)alloc(64 * 4);
  int*    cnt1  = (int*)alloc(16 * 4);
  int*    off1  = (int*)alloc(16 * 4);
  int*    mem0  = (int*)alloc((size_t)CCH * 4);
  int*    mem1  = (int*)alloc((size_t)CCH * 4);
  int*    rs0   = (int*)alloc((size_t)CCH * 8 * 4);
  int*    rs1   = (int*)alloc((size_t)CCH * 8 * 4);
  int*    inv1  = (int*)alloc((size_t)NSL * 4);
  float*  sn2h  = (float*)alloc((size_t)2 * NSL * 4);
  uint4*  Bfrag0 = (uint4*)alloc((size_t)32 * 28 * 64 * 16);
  uint4*  Bfrag1 = (uint4*)alloc((size_t)8 * 28 * 64 * 16);
  uint4*  Y0    = (uint4*)alloc((size_t)8 * 256 * 28 * 64 * 16);   // 58.7 MB
  uint4*  Y1    = (uint4*)alloc((size_t)8 * CCH * 112 * 16);       // 58.7 MB
  float*  P8_0  = (float*)alloc((size_t)8 * CCH * 64 * 4);
  float*  P8_1  = (float*)alloc((size_t)8 * CCH * 16 * 4);
  double* cl0   = (double*)alloc(64 * 8);
  double* cl1   = (double*)alloc(16 * 8);

  k_setup<<<80, 64, 0, stream>>>(im0, im1, cnt0, off0, cnt1, off1, mem0, mem1, rs0, rs1, inv1);
  k_brep<<<10, 256, 0, stream>>>(X, off0, off1, rs0, rs1, Bfrag0, Bfrag1);
  k_pack<<<dim3(256, 8, 2), 256, 0, stream>>>(X, rs0, inv1, Y0, Y1, sn2h);
  k_gemm_all<<<dim3(192, 8), 256, 0, stream>>>(Y0, Y1, Bfrag0, Bfrag1, P8_0, P8_1);
  k_fin_all<<<80, 512, 0, stream>>>(P8_0, P8_1, sn2h, rs0, rs1, cnt0, off0, cnt1, off1, cl0, cl1);
  k_final<<<1, 64, 0, stream>>>(cl0, cl1, out);
}

// Round 11
// 99.015 us; speedup vs baseline: 1.2732x; 1.2145x over previous
//
#include <hip/hip_runtime.h>
#include <math.h>

#define CCH 4096
#define SP 891
#define NSL 32768

typedef __attribute__((ext_vector_type(8))) short short8;
typedef __attribute__((ext_vector_type(4))) float f32x4;

__device__ __forceinline__ unsigned int pack_bf2(float a, float b) {
  unsigned int ua = __builtin_bit_cast(unsigned int, a);
  unsigned int ub = __builtin_bit_cast(unsigned int, b);
  ua = (ua + 0x7fffu + ((ua >> 16) & 1u)) >> 16;
  ub = (ub + 0x7fffu + ((ub >> 16) & 1u)) >> 16;
  return ua | (ub << 16);
}

// ---------- setup: members + rowSid + cnt/off (80 blocks x 64) ----------
__global__ void k_setup(const int* __restrict__ im0, const int* __restrict__ im1,
                        int* cnt0, int* off0, int* cnt1, int* off1,
                        int* mem0, int* mem1, int* rs0, int* rs1) {
  int cb = blockIdx.x;
  int level = (cb >= 64) ? 1 : 0;
  int c = level ? cb - 64 : cb;
  const int* im = level ? im1 : im0;
  int* members = level ? mem1 : mem0;
  int* rs = level ? rs1 : rs0;
  int lane = threadIdx.x;  // 64
  int lt = 0;
  for (int ch = lane; ch < CCH; ch += 64) lt += (im[ch] < c) ? 1 : 0;
  for (int o = 32; o; o >>= 1) lt += __shfl_xor(lt, o, 64);
  int base = lt;
  int cnt = 0;
  for (int chunk = 0; chunk < CCH; chunk += 64) {
    int ch = chunk + lane;
    bool m = (im[ch] == c);
    unsigned long long mk = __ballot(m);
    int pos = __popcll(mk & ((1ull << lane) - 1ull));
    if (m) members[base + cnt + pos] = ch;
    cnt += __popcll(mk);
  }
  int n = cnt;
  if (lane == 0) {
    if (level) { cnt1[c] = n; off1[c] = base; }
    else       { cnt0[c] = n; off0[c] = base; }
  }
  __syncthreads();
  for (int r = lane; r < n; r += 64) {
    #pragma unroll
    for (int q = 0; q < 8; q++) {
      int p = 8 * r + q;
      int b = p / n, j = p - b * n;
      rs[(size_t)(base + r) * 8 + q] = b * CCH + members[base + j];
    }
  }
}

// ---------- pack rep slices into fragment-major bf16 tables (B operands) ----------
__global__ void k_brep(const float* __restrict__ X,
    const int* __restrict__ off0, const int* __restrict__ off1,
    const int* __restrict__ rs0, const int* __restrict__ rs1,
    uint4* __restrict__ Bfrag0, uint4* __restrict__ Bfrag1) {
  int gid = blockIdx.x * 4 + (threadIdx.x >> 6);  // 0..39
  int l = threadIdx.x & 63;
  int lrow = l & 15, hi = l >> 4;
  int level = (gid >= 32) ? 1 : 0;
  int q = level ? (gid - 32) : (gid >> 2);
  int ct = level ? 0 : (gid & 3);
  int cc = ct * 16 + lrow;
  int base = level ? off1[cc] : off0[cc];
  int sid = (level ? rs1 : rs0)[(size_t)base * 8 + q];
  const float* ap = X + (size_t)sid * SP + hi * 8;
  uint4* dst = (level ? Bfrag1 + (size_t)(q * 28) * 64
                      : Bfrag0 + (size_t)((q * 4 + ct) * 28) * 64) + l;
  #pragma unroll 3
  for (int kc = 0; kc < 27; kc++) {
    float4 fa0 = *(const float4*)(ap + kc * 32);
    float4 fa1 = *(const float4*)(ap + kc * 32 + 4);
    uint4 ua;
    ua.x = pack_bf2(fa0.x, fa0.y); ua.y = pack_bf2(fa0.z, fa0.w);
    ua.z = pack_bf2(fa1.x, fa1.y); ua.w = pack_bf2(fa1.z, fa1.w);
    dst[kc * 64] = ua;
  }
  {
    float4 fa0, fa1;
    if (hi == 3) {
      fa0 = make_float4(ap[864], ap[865], ap[866], 0.f);
      fa1 = make_float4(0.f, 0.f, 0.f, 0.f);
    } else {
      fa0 = *(const float4*)(ap + 864);
      fa1 = *(const float4*)(ap + 868);
    }
    uint4 ua;
    ua.x = pack_bf2(fa0.x, fa0.y); ua.y = pack_bf2(fa0.z, fa0.w);
    ua.z = pack_bf2(fa1.x, fa1.y); ua.w = pack_bf2(fa1.z, fa1.w);
    dst[27 * 64] = ua;
  }
}

// ---------- fused transpose-in-LDS MFMA GEMM, both levels (grid 512 x 8) ----------
// Block: 16-row tile. Phase1: 16 slices -> swizzled LDS bf16 (one pass over X),
// fused sn2 (L0 only). One barrier. Phase3: 28 MFMA k-steps, B from L2 tables.
__global__ __launch_bounds__(256) void k_gemm_all(const float* __restrict__ X,
    const int* __restrict__ rs0, const int* __restrict__ rs1,
    const uint4* __restrict__ Bfrag0, const uint4* __restrict__ Bfrag1,
    float* __restrict__ P8_0, float* __restrict__ P8_1, float* __restrict__ sn2) {
  __shared__ __align__(16) unsigned short T[16 * 896];   // 28 KB
  __shared__ int s_sid[16];
  const int q = blockIdx.y, tid = threadIdx.x;
  const int lev = blockIdx.x >> 8;
  const int rt = blockIdx.x & 255;
  const int* rs = lev ? rs1 : rs0;
  if (tid < 16) s_sid[tid] = rs[(size_t)(rt * 16 + tid) * 8 + q];
  __syncthreads();
  // ---- phase 1: load + pack + swizzled LDS transpose ----
  const int i = tid >> 4, j = tid & 15;
  const float* sp = X + (size_t)s_sid[i] * SP;
  char* Ti = (char*)(T + i * 896);
  const int isw = (i & 7) << 4;
  float s2 = 0.f;
  #pragma unroll
  for (int kcc = 0; kcc < 7; kcc++) {
    int cidx = kcc * 16 + j;
    int el = cidx * 8;
    float4 v0, v1;
    if (cidx < 111) {
      v0 = *(const float4*)(sp + el);
      v1 = *(const float4*)(sp + el + 4);
    } else {
      v0 = make_float4(sp[888], sp[889], sp[890], 0.f);
      v1 = make_float4(0.f, 0.f, 0.f, 0.f);
    }
    s2 += v0.x * v0.x + v0.y * v0.y + v0.z * v0.z + v0.w * v0.w
        + v1.x * v1.x + v1.y * v1.y + v1.z * v1.z + v1.w * v1.w;
    uint4 u;
    u.x = pack_bf2(v0.x, v0.y); u.y = pack_bf2(v0.z, v0.w);
    u.z = pack_bf2(v1.x, v1.y); u.w = pack_bf2(v1.z, v1.w);
    *(uint4*)(Ti + ((cidx * 16) ^ isw)) = u;
  }
  if (!lev) {
    s2 += __shfl_xor(s2, 1, 16); s2 += __shfl_xor(s2, 2, 16);
    s2 += __shfl_xor(s2, 4, 16); s2 += __shfl_xor(s2, 8, 16);
    if (j == 0) sn2[s_sid[i]] = s2;
  }
  __syncthreads();
  // ---- phase 3: MFMA ----
  const int l = tid & 63, w = tid >> 6;
  const int lrow = l & 15, hi = l >> 4;
  const char* Abase = (const char*)T + lrow * 1792;
  const int rsw = (lrow & 7) << 4;
  if (!lev) {
    // L0: tile 16 x 64; wave w owns col-frag w
    const uint4* bq = Bfrag0 + (size_t)((q * 4 + w) * 28) * 64 + l;
    f32x4 acc = {0.f, 0.f, 0.f, 0.f};
    short8 A0, A1;
    uint4 B0, B1, B2, B3;
    A0 = *(const short8*)(Abase + ((0 * 64 + hi * 16) ^ rsw));
    A1 = *(const short8*)(Abase + ((1 * 64 + hi * 16) ^ rsw));
    B0 = bq[0 * 64]; B1 = bq[1 * 64]; B2 = bq[2 * 64]; B3 = bq[3 * 64];
    #pragma unroll
    for (int kc = 0; kc < 28; kc++) {
      short8 a = (kc & 1) ? A1 : A0;
      uint4 b = (kc & 3) == 0 ? B0 : (kc & 3) == 1 ? B1 : (kc & 3) == 2 ? B2 : B3;
      acc = __builtin_amdgcn_mfma_f32_16x16x32_bf16(a, __builtin_bit_cast(short8, b), acc, 0, 0, 0);
      if (kc + 2 < 28) {
        short8 an = *(const short8*)(Abase + (((kc + 2) * 64 + hi * 16) ^ rsw));
        if (kc & 1) A1 = an; else A0 = an;
      }
      if (kc + 4 < 28) {
        uint4 bn = bq[(kc + 4) * 64];
        switch (kc & 3) { case 0: B0 = bn; break; case 1: B1 = bn; break;
                          case 2: B2 = bn; break; default: B3 = bn; }
      }
    }
    #pragma unroll
    for (int r = 0; r < 4; r++) {
      int row = rt * 16 + hi * 4 + r;
      P8_0[((size_t)q * CCH + row) * 64 + w * 16 + lrow] = acc[r];
    }
  } else {
    // L1: tile 16 x 16; k split across 4 waves, LDS reduce
    const uint4* bq = Bfrag1 + (size_t)(q * 28) * 64 + l;
    f32x4 acc = {0.f, 0.f, 0.f, 0.f};
    #pragma unroll
    for (int kk = 0; kk < 7; kk++) {
      int kc = w * 7 + kk;
      short8 a = *(const short8*)(Abase + ((kc * 64 + hi * 16) ^ rsw));
      uint4 b = bq[kc * 64];
      acc = __builtin_amdgcn_mfma_f32_16x16x32_bf16(a, __builtin_bit_cast(short8, b), acc, 0, 0, 0);
    }
    __syncthreads();
    float4* Tf = (float4*)T;
    Tf[w * 64 + l] = make_float4(acc[0], acc[1], acc[2], acc[3]);
    __syncthreads();
    if (w == 0) {
      float4 v0 = Tf[l], v1 = Tf[64 + l], v2 = Tf[128 + l], v3 = Tf[192 + l];
      float vr[4] = { v0.x + v1.x + v2.x + v3.x, v0.y + v1.y + v2.y + v3.y,
                      v0.z + v1.z + v2.z + v3.z, v0.w + v1.w + v2.w + v3.w };
      #pragma unroll
      for (int r = 0; r < 4; r++) {
        int row = rt * 16 + hi * 4 + r;
        P8_1[((size_t)q * CCH + row) * 16 + lrow] = vr[r];
      }
    }
  }
}

// ---------- per-cluster epilogue (512 threads), both levels in one dispatch ----------
template<int K>
__device__ __forceinline__ void fin_body(const float* __restrict__ P8,
    const float* __restrict__ sn2, const int* __restrict__ rs,
    const int* __restrict__ cnt, const int* __restrict__ off,
    double* __restrict__ clLoss, int c) {
  __shared__ float pcc[4096];
  __shared__ float red[512];
  __shared__ double redd[512];
  __shared__ float s_conc;
  const int n = cnt[c], base = off[c];
  const int tid = threadIdx.x;
  float rn0 = 0.f;
  #pragma unroll
  for (int qq = 0; qq < 8; qq++) rn0 += sn2[rs[(size_t)base * 8 + qq]];
  float t = 0.f;
  for (int r = tid; r < n; r += 512) {
    float pd = 0.f, rn = 0.f;
    #pragma unroll
    for (int qq = 0; qq < 8; qq++) {
      pd += P8[((size_t)qq * CCH + base + r) * K + c];
      rn += sn2[rs[(size_t)(base + r) * 8 + qq]];
    }
    pcc[r] = pd;
    if (r > 0) {
      float d2 = rn - 2.f * pd + rn0;
      t += (d2 > 0.f) ? sqrtf(d2) : 0.f;
    }
  }
  red[tid] = t; __syncthreads();
  for (int o = 256; o; o >>= 1) { if (tid < o) red[tid] += red[tid + o]; __syncthreads(); }
  if (tid == 0) s_conc = red[0] / ((float)n * logf((float)n + 10.f));
  __syncthreads();
  const float invc = 1.f / s_conc;
  const int wv = tid >> 6, lane = tid & 63;
  const int sub = (K == 64) ? 0 : (lane >> 4);
  const int cc = lane & (K - 1);
  constexpr int RPI = 8 * (64 / K);
  double acc = 0.0;
  for (int r = wv * (64 / K) + sub; r < n; r += RPI) {
    float s = 0.f;
    #pragma unroll
    for (int qq = 0; qq < 8; qq++) s += P8[((size_t)qq * CCH + base + r) * K + cc];
    float lg = s * invc;
    float m = lg;
    #pragma unroll
    for (int o = K / 2; o; o >>= 1) m = fmaxf(m, __shfl_xor(m, o, K));
    float e = expf(lg - m);
    float se = e;
    #pragma unroll
    for (int o = K / 2; o; o >>= 1) se += __shfl_xor(se, o, K);
    if (cc == 0) acc += (double)(m + logf(se)) - (double)(pcc[r] * invc);
  }
  redd[tid] = acc; __syncthreads();
  for (int o = 256; o; o >>= 1) { if (tid < o) redd[tid] += redd[tid + o]; __syncthreads(); }
  if (tid == 0) clLoss[c] = redd[0] / (double)n;
}

__global__ __launch_bounds__(512) void k_fin_all(const float* __restrict__ P8_0,
    const float* __restrict__ P8_1, const float* __restrict__ sn2,
    const int* __restrict__ rs0, const int* __restrict__ rs1,
    const int* __restrict__ cnt0, const int* __restrict__ off0,
    const int* __restrict__ cnt1, const int* __restrict__ off1,
    double* __restrict__ cl0, double* __restrict__ cl1) {
  if (blockIdx.x < 64) fin_body<64>(P8_0, sn2, rs0, cnt0, off0, cl0, blockIdx.x);
  else                 fin_body<16>(P8_1, sn2, rs1, cnt1, off1, cl1, blockIdx.x - 64);
}

// ---------- final scalars ----------
__global__ void k_final(const double* __restrict__ cl0, const double* __restrict__ cl1,
                        float* __restrict__ out) {
  if (threadIdx.x == 0) {
    double s0 = 0.0, s1 = 0.0;
    for (int i = 0; i < 64; i++) s0 += cl0[i];
    for (int i = 0; i < 16; i++) s1 += cl1[i];
    out[0] = (float)(s0 / 4096.0);
    out[1] = (float)(s1 / 8192.0);
  }
}

extern "C" void kernel_launch(void* const* d_in, const int* in_sizes, int n_in,
                              void* d_out, int out_size, void* d_ws, size_t ws_size,
                              hipStream_t stream) {
  const float* X = (const float*)d_in[0];
  const int* im0 = (const int*)d_in[1];
  const int* im1 = (const int*)d_in[2];
  float* out = (float*)d_out;

  char* w = (char*)d_ws;
  auto alloc = [&](size_t bytes) -> char* {
    char* p = w; w += (bytes + 255) & ~(size_t)255; return p;
  };
  int*    cnt0  = (int*)alloc(64 * 4);
  int*    off0  = (int*)alloc(64 * 4);
  int*    cnt1  = (int*)alloc(16 * 4);
  int*    off1  = (int*)alloc(16 * 4);
  int*    mem0  = (int*)alloc((size_t)CCH * 4);
  int*    mem1  = (int*)alloc((size_t)CCH * 4);
  int*    rs0   = (int*)alloc((size_t)CCH * 8 * 4);
  int*    rs1   = (int*)alloc((size_t)CCH * 8 * 4);
  float*  sn2   = (float*)alloc((size_t)NSL * 4);
  uint4*  Bfrag0 = (uint4*)alloc((size_t)32 * 28 * 64 * 16);
  uint4*  Bfrag1 = (uint4*)alloc((size_t)8 * 28 * 64 * 16);
  float*  P8_0  = (float*)alloc((size_t)8 * CCH * 64 * 4);
  float*  P8_1  = (float*)alloc((size_t)8 * CCH * 16 * 4);
  double* cl0   = (double*)alloc(64 * 8);
  double* cl1   = (double*)alloc(16 * 8);

  k_setup<<<80, 64, 0, stream>>>(im0, im1, cnt0, off0, cnt1, off1, mem0, mem1, rs0, rs1);
  k_brep<<<10, 256, 0, stream>>>(X, off0, off1, rs0, rs1, Bfrag0, Bfrag1);
  k_gemm_all<<<dim3(512, 8), 256, 0, stream>>>(X, rs0, rs1, Bfrag0, Bfrag1, P8_0, P8_1, sn2);
  k_fin_all<<<80, 512, 0, stream>>>(P8_0, P8_1, sn2, rs0, rs1, cnt0, off0, cnt1, off1, cl0, cl1);
  k_final<<<1, 64, 0, stream>>>(cl0, cl1, out);
}